// Round 16
// baseline (2735.709 us; speedup 1.0000x reference)
//
#include <hip/hip_runtime.h>

// TerminalGRU: B=256 T=256 D=512 H=1024 C=128
// Round-16: R15's XCD-local gamble FAILED (bid&7 co-residency false) -> back to
// the PROVEN agent-atomic (MALL) transport, but merge notify INTO the data:
// ring slots are pre-POISONED (0xFF.. = all-NaN bf16, impossible as h output)
// by a tiny dispatch between combo(c-1) and scan(c) (stream-order = the same
// kernel-boundary guarantee used since R2). Consumers poll the h words
// themselves with agent atomic loads -- the successful poll RETURNS the data.
// Deletes producer vmcnt-drain + notify store + separate fragment loads
// (~2us/step of MALL RTTs). Accumulation order unchanged -> bit-identical.
// Pipeline: prep+cvtX -> gates(0) -> loop{ [poison(c)]; scan(c); combo(c) }

#define DEVI __device__ __forceinline__

typedef __bf16 bf16x8 __attribute__((ext_vector_type(8)));
typedef float f32x4 __attribute__((ext_vector_type(4)));
typedef unsigned long long u64;

static constexpr int Bb = 256, Tt = 256, Dd = 512, Hh = 1024, Cc = 128;
static constexpr int G3 = 3072, DC = 640, TC = 32, NC = Tt / TC;
static constexpr int SLOTS = TC + 1;  // 33-slot h ring
static constexpr int LDP = 72;        // LDS row stride (64 + 8 pad)
static constexpr u64 POIS = 0xFFFFFFFFFFFFFFFFull;  // 4x bf16 NaN

DEVI unsigned short f2b(float f) {
  union { float f; unsigned u; } v; v.f = f;
  unsigned r = v.u + 0x7FFFu + ((v.u >> 16) & 1u);
  return (unsigned short)(r >> 16);
}
DEVI float b2f(unsigned short h) {
  union { unsigned u; float f; } v; v.u = ((unsigned)h) << 16; return v.f;
}

union HQ { u64 q[2]; bf16x8 v; };

// ---------------- prep kernels ----------------

__global__ __launch_bounds__(256) void k_cvt(const float* __restrict__ x,
                                             unsigned short* __restrict__ o, int n) {
  int i = (blockIdx.x * 256 + threadIdx.x) * 8;
  if (i >= n) return;
  float4 a = *(const float4*)(x + i), b = *(const float4*)(x + i + 4);
  uint4 u;
  u.x = (unsigned)f2b(a.x) | ((unsigned)f2b(a.y) << 16);
  u.y = (unsigned)f2b(a.z) | ((unsigned)f2b(a.w) << 16);
  u.z = (unsigned)f2b(b.x) | ((unsigned)f2b(b.y) << 16);
  u.w = (unsigned)f2b(b.z) | ((unsigned)f2b(b.w) << 16);
  *(uint4*)(o + i) = u;
}

__global__ __launch_bounds__(256) void k_cvt_wa(const float* __restrict__ Wih,
                                                unsigned short* __restrict__ Wa) {
  int u = blockIdx.x * 256 + threadIdx.x;
  int g = u >> 6, d = (u & 63) * 8;
  const float* p = Wih + (size_t)g * DC + d;
  float4 a = *(const float4*)p, b = *(const float4*)(p + 4);
  uint4 o;
  o.x = (unsigned)f2b(a.x) | ((unsigned)f2b(a.y) << 16);
  o.y = (unsigned)f2b(a.z) | ((unsigned)f2b(a.w) << 16);
  o.z = (unsigned)f2b(b.x) | ((unsigned)f2b(b.y) << 16);
  o.w = (unsigned)f2b(b.z) | ((unsigned)f2b(b.w) << 16);
  *(uint4*)(Wa + (size_t)g * Dd + d) = o;
}

__global__ __launch_bounds__(256) void k_cvt_wct(const float* __restrict__ Wih,
                                                 unsigned short* __restrict__ WcT) {
  int g = blockIdx.x * 256 + threadIdx.x;
  int c = blockIdx.y;
  WcT[(size_t)c * G3 + g] = f2b(Wih[(size_t)g * DC + Dd + c]);
}

__global__ __launch_bounds__(256) void k_pid(const float* __restrict__ ts,
                                             int* __restrict__ pid) {
  int bt = blockIdx.x * 256 + threadIdx.x;
  int t = bt & (Tt - 1);
  if (t == 0) { pid[bt] = -1; return; }
  const float* p = ts + (size_t)(bt - 1) * Cc;
  int id = 0;
  for (int c = 0; c < Cc; c += 4) {
    float4 v = *(const float4*)(p + c);
    if (v.x > 0.5f) id = c;
    if (v.y > 0.5f) id = c + 1;
    if (v.z > 0.5f) id = c + 2;
    if (v.w > 0.5f) id = c + 3;
  }
  pid[bt] = id;
}

// poison the 32 ring slots scan(chunk at t0) will write: slots (t0+1..t0+32)%33
__global__ __launch_bounds__(256) void k_poison(u64* __restrict__ hring, int t0) {
  int sidx = blockIdx.x >> 6;  // 0..31 (grid 2048)
  int slot = (t0 + 1 + sidx) % SLOTS;
  u64* p = hring + (size_t)slot * (Bb * Hh / 4)
         + (size_t)(blockIdx.x & 63) * 1024 + (size_t)threadIdx.x * 4;
  uint4 v; v.x = v.y = v.z = v.w = 0xFFFFFFFFu;
  *(uint4*)p = v;
}

// ---------------- gates tile: reg-staged LDS, BK=64 (R13 proven) ----------------
DEVI void gates_tile(int mi, int ni, const unsigned short* __restrict__ Xb,
                     const unsigned short* __restrict__ Wa,
                     const unsigned short* __restrict__ WcT,
                     const float* __restrict__ bih,
                     const int* __restrict__ pid,
                     unsigned short* __restrict__ gx, int t0c,
                     unsigned short* sA, unsigned short* sB) {
  const int m0 = mi * 128, n0 = ni * 128;
  const int tid = threadIdx.x;
  const int l = tid & 63, w = tid >> 6;
  const int wm = w >> 1, wn = w & 1;
  const int r0l = 64 * wm, c0l = 64 * wn;
  const int lr = l & 15, lk = (l >> 4) * 8;

  int srow[4], sq[4];
  size_t gA[4], gB[4];
#pragma unroll
  for (int c = 0; c < 4; ++c) {
    int ch = tid + c * 256;
    srow[c] = ch >> 3; sq[c] = ch & 7;
    int mrow = m0 + srow[c];
    gA[c] = ((size_t)((mrow >> 5) * Tt + t0c + (mrow & 31))) * Dd + sq[c] * 8;
    gB[c] = (size_t)(n0 + srow[c]) * Dd + sq[c] * 8;
  }

  f32x4 acc[4][4] = {};
  for (int ks = 0; ks < 8; ++ks) {
    int k0 = ks * 64;
    __syncthreads();
#pragma unroll
    for (int c = 0; c < 4; ++c) {
      bf16x8 av = *(const bf16x8*)(Xb + gA[c] + k0);
      bf16x8 bv = *(const bf16x8*)(Wa + gB[c] + k0);
      *(bf16x8*)(sA + srow[c] * LDP + sq[c] * 8) = av;
      *(bf16x8*)(sB + srow[c] * LDP + sq[c] * 8) = bv;
    }
    __syncthreads();
#pragma unroll
    for (int kk = 0; kk < 2; ++kk) {
      int kc = kk * 32 + lk;
      bf16x8 a[4], b[4];
#pragma unroll
      for (int mf = 0; mf < 4; ++mf)
        a[mf] = *(const bf16x8*)(sA + (r0l + 16 * mf + lr) * LDP + kc);
#pragma unroll
      for (int nf = 0; nf < 4; ++nf)
        b[nf] = *(const bf16x8*)(sB + (c0l + 16 * nf + lr) * LDP + kc);
#pragma unroll
      for (int mf = 0; mf < 4; ++mf)
#pragma unroll
        for (int nf = 0; nf < 4; ++nf)
          acc[mf][nf] = __builtin_amdgcn_mfma_f32_16x16x32_bf16(a[mf], b[nf], acc[mf][nf], 0, 0, 0);
    }
  }

  const int ri = (l >> 4) * 4;
  const int r0 = m0 + 64 * wm, c0 = n0 + 64 * wn;
  for (int mf = 0; mf < 4; ++mf) {
    int rowb = r0 + 16 * mf + ri;
    int pd[4];
#pragma unroll
    for (int i = 0; i < 4; ++i) {
      int rr = rowb + i;
      pd[i] = pid[(size_t)(rr >> 5) * Tt + t0c + (rr & 31)];
    }
    for (int nf = 0; nf < 4; ++nf) {
      int g = c0 + 16 * nf + lr;
      float bi = bih[g];
#pragma unroll
      for (int i = 0; i < 4; ++i) {
        float v = acc[mf][nf][i] + bi;
        if (pd[i] >= 0) v += b2f(WcT[(size_t)pd[i] * G3 + g]);
        gx[(size_t)(rowb + i) * G3 + g] = f2b(v);
      }
    }
  }
}

__global__ __launch_bounds__(256) void k_gates(const unsigned short* __restrict__ Xb,
                                               const unsigned short* __restrict__ Wa,
                                               const unsigned short* __restrict__ WcT,
                                               const float* __restrict__ bih,
                                               const int* __restrict__ pid,
                                               unsigned short* __restrict__ gx, int t0c) {
  __shared__ unsigned short sA[128 * LDP], sB[128 * LDP];
  gates_tile(blockIdx.x, blockIdx.y, Xb, Wa, WcT, bih, pid, gx, t0c, sA, sB);
}

// ---------------- logits tile (reads h straight from the ring) ----------------
DEVI void logits_tile(int blk, const unsigned short* __restrict__ hring,
                      const unsigned short* __restrict__ Wo,
                      const float* __restrict__ bout,
                      float* __restrict__ out, int t0) {
  int l = threadIdx.x & 63, w = threadIdx.x >> 6;
  int lr = l & 15, lk = (l >> 4) * 8;
  int r0 = blk * 64 + 16 * w;
  int am = r0 + lr;
  int ab = am >> 5, atl = am & 31;
  const unsigned short* arow =
      hring + (size_t)((t0 + atl + 1) % SLOTS) * (Bb * Hh) + (size_t)ab * Hh;
  f32x4 acc[8] = {};
  for (int kk = 0; kk < 32; ++kk) {
    int k = kk * 32 + lk;
    bf16x8 a = *(const bf16x8*)(arow + k);
#pragma unroll
    for (int nf = 0; nf < 8; ++nf) {
      bf16x8 b = *(const bf16x8*)(Wo + (size_t)(16 * nf + lr) * Hh + k);
      acc[nf] = __builtin_amdgcn_mfma_f32_16x16x32_bf16(a, b, acc[nf], 0, 0, 0);
    }
  }
  int ri = (l >> 4) * 4;
  for (int nf = 0; nf < 8; ++nf) {
    int c = 16 * nf + lr;
    float bo = bout[c];
#pragma unroll
    for (int i = 0; i < 4; ++i) {
      int m = r0 + ri + i;
      int grow = (m >> 5) * Tt + t0 + (m & 31);
      out[(size_t)grow * Cc + c] = acc[nf][i] + bo;
    }
  }
}

// ---------------- combo: gates(c+1) + logits(c) ----------------
__global__ __launch_bounds__(256) void k_combo(
    const unsigned short* __restrict__ Xb, const unsigned short* __restrict__ Wa,
    const unsigned short* __restrict__ WcT, const float* __restrict__ bih,
    const int* __restrict__ pid, unsigned short* __restrict__ gxNext, int doGates,
    const unsigned short* __restrict__ hring, const unsigned short* __restrict__ Wob,
    const float* __restrict__ bou, float* __restrict__ outp, int t0) {
  __shared__ unsigned short sA[128 * LDP], sB[128 * LDP];
  int bid = blockIdx.x;
  if (bid < 1536) {
    if (doGates)
      gates_tile(bid & 63, bid >> 6, Xb, Wa, WcT, bih, pid, gxNext, t0 + TC, sA, sB);
  } else {
    logits_tile(bid - 1536, hring, Wob, bou, outp, t0);
  }
}

// ---------------- recurrent scan chunk (data-as-flag handshake) ----------------
// 256 blocks x 256 threads. mg = bid&7 (rows [32mg,+32)), cb = bid>>3
// (hcols [32cb,+32)). Wave w K-slice [256w,+256) = producers 8w..8w+7.
// Consumers poll the h words themselves (agent atomic 8B loads) until
// != POISON -- the successful poll IS the data load. Ring slots for this
// launch were poisoned by k_poison (stream-ordered before this kernel).
__global__ __launch_bounds__(256, 1) void k_scan(const unsigned short* __restrict__ Whh,
                                                 const float* __restrict__ bhh,
                                                 const unsigned short* __restrict__ gx,
                                                 unsigned short* __restrict__ hring,
                                                 int t0) {
  __shared__ float red[4 * 32 * 100];  // [wave][row32][3*32 pad100] = 51.2KB
  const int tid = threadIdx.x;
  const int l = tid & 63, w = tid >> 6;
  const int bid = blockIdx.x;
  const int mg = bid & 7, cb = bid >> 3;
  const int lr = l & 15, lk = (l >> 4) * 8;
  const int hcolBase = 32 * cb;
  const int ri = (l >> 4) * 4;

  bf16x8 Breg[6][8];
#pragma unroll
  for (int nf = 0; nf < 6; ++nf) {
    int wrow = (nf >> 1) * Hh + hcolBase + (nf & 1) * 16 + lr;
#pragma unroll
    for (int kk = 0; kk < 8; ++kk) {
      int k = 256 * w + 32 * kk + lk;
      Breg[nf][kk] = *(const bf16x8*)(Whh + (size_t)wrow * Hh + k);
    }
  }

  const int erow = tid >> 3, ej0 = (tid & 7) * 4;
  const int eb = 32 * mg + erow;
  const int ecol = hcolBase + ej0;
  const float4 bhr4 = *(const float4*)(bhh + ecol);
  const float4 bhz4 = *(const float4*)(bhh + Hh + ecol);
  const float4 bhn4 = *(const float4*)(bhh + 2 * Hh + ecol);

  u64 hsave = 0;

  for (int tl = 0; tl < TC; ++tl) {
    const int t = t0 + tl;
    const unsigned short* hcur = hring + (size_t)(t % SLOTS) * (Bb * Hh);
    u64* hnq = (u64*)hring + (size_t)((t + 1) % SLOTS) * (Bb * Hh / 4);

    const size_t gxo = (size_t)(eb * TC + tl) * G3;
    uint2 gr = *(const uint2*)(gx + gxo + ecol);
    uint2 gz = *(const uint2*)(gx + gxo + Hh + ecol);
    uint2 gn = *(const uint2*)(gx + gxo + 2 * Hh + ecol);

    u64 hprev = (tl == 0) ? *(const u64*)(hcur + (size_t)eb * Hh + ecol) : hsave;

    // poll-load A fragments in 2 batches of 4 kk (pipelined loads, 1 RTT/detect).
    // At tl==0 the slot holds the previous launch's h (never poison) -> exits
    // after one iteration. Bounded: on timeout we proceed (clean absmax fail).
    f32x4 acc[2][6] = {};
    const u64* base0 = (const u64*)hcur + ((size_t)(32 * mg + lr) << 8);
    const u64* base1 = base0 + (16 << 8);
    const int kq = 64 * w + (lk >> 2);
#pragma unroll
    for (int bt = 0; bt < 2; ++bt) {
      u64 q0[4][2], q1[4][2];
      int done = 0;
      for (int it = 0; it < (1 << 18) && !done; ++it) {
        int ok = 1;
#pragma unroll
        for (int j = 0; j < 4; ++j) {
          int o = kq + 8 * (4 * bt + j);
          q0[j][0] = __hip_atomic_load(base0 + o,     __ATOMIC_RELAXED, __HIP_MEMORY_SCOPE_AGENT);
          q0[j][1] = __hip_atomic_load(base0 + o + 1, __ATOMIC_RELAXED, __HIP_MEMORY_SCOPE_AGENT);
          q1[j][0] = __hip_atomic_load(base1 + o,     __ATOMIC_RELAXED, __HIP_MEMORY_SCOPE_AGENT);
          q1[j][1] = __hip_atomic_load(base1 + o + 1, __ATOMIC_RELAXED, __HIP_MEMORY_SCOPE_AGENT);
        }
#pragma unroll
        for (int j = 0; j < 4; ++j)
          ok &= (int)((q0[j][0] != POIS) & (q0[j][1] != POIS) &
                      (q1[j][0] != POIS) & (q1[j][1] != POIS));
        done = __all(ok);
      }
#pragma unroll
      for (int j = 0; j < 4; ++j) {
        HQ h0, h1;
        h0.q[0] = q0[j][0]; h0.q[1] = q0[j][1];
        h1.q[0] = q1[j][0]; h1.q[1] = q1[j][1];
        int kk = 4 * bt + j;
#pragma unroll
        for (int nf = 0; nf < 6; ++nf) {
          acc[0][nf] = __builtin_amdgcn_mfma_f32_16x16x32_bf16(h0.v, Breg[nf][kk], acc[0][nf], 0, 0, 0);
          acc[1][nf] = __builtin_amdgcn_mfma_f32_16x16x32_bf16(h1.v, Breg[nf][kk], acc[1][nf], 0, 0, 0);
        }
      }
    }

    // partials -> LDS (col = gate*32 + half*16 + lr)
#pragma unroll
    for (int mf = 0; mf < 2; ++mf)
#pragma unroll
      for (int nf = 0; nf < 6; ++nf)
#pragma unroll
        for (int i = 0; i < 4; ++i)
          red[(w * 32 + 16 * mf + ri + i) * 100 + (nf >> 1) * 32 + (nf & 1) * 16 + lr] = acc[mf][nf][i];
    __syncthreads();

    f32x4 vr = {}, vz = {}, vn = {};
#pragma unroll
    for (int w2 = 0; w2 < 4; ++w2) {
      const float* rp = &red[(w2 * 32 + erow) * 100];
      vr += *(const f32x4*)(rp + ej0);
      vz += *(const f32x4*)(rp + 32 + ej0);
      vn += *(const f32x4*)(rp + 64 + ej0);
    }
    unsigned short grs[4] = {(unsigned short)gr.x, (unsigned short)(gr.x >> 16),
                             (unsigned short)gr.y, (unsigned short)(gr.y >> 16)};
    unsigned short gzs[4] = {(unsigned short)gz.x, (unsigned short)(gz.x >> 16),
                             (unsigned short)gz.y, (unsigned short)(gz.y >> 16)};
    unsigned short gns[4] = {(unsigned short)gn.x, (unsigned short)(gn.x >> 16),
                             (unsigned short)gn.y, (unsigned short)(gn.y >> 16)};
    u64 ho = 0;
#pragma unroll
    for (int i = 0; i < 4; ++i) {
      float hr = vr[i] + (&bhr4.x)[i];
      float hz = vz[i] + (&bhz4.x)[i];
      float hn = vn[i] + (&bhn4.x)[i];
      float xr = b2f(grs[i]), xz = b2f(gzs[i]), xn = b2f(gns[i]);
      float rg = 1.f / (1.f + __expf(-(xr + hr)));
      float zg = 1.f / (1.f + __expf(-(xz + hz)));
      float pre = xn + rg * hn;
      pre = fminf(fmaxf(pre, -15.f), 15.f);
      float e = __expf(-2.f * pre);
      float ng = (1.f - e) / (1.f + e);
      float hp = b2f((unsigned short)(hprev >> (16 * i)));
      float hv = (1.f - zg) * ng + zg * hp;
      ho |= (u64)f2b(hv) << (16 * i);
    }
    // the store IS the notification (consumers poll this word)
    __hip_atomic_store(hnq + ((size_t)eb * Hh + ecol) / 4, ho,
                       __ATOMIC_RELAXED, __HIP_MEMORY_SCOPE_AGENT);
    hsave = ho;

    __syncthreads();  // red[] reuse protection only
  }
}

// ---------------- launch ----------------
extern "C" void kernel_launch(void* const* d_in, const int* in_sizes, int n_in,
                              void* d_out, int out_size, void* d_ws, size_t ws_size,
                              hipStream_t stream) {
  const float* gru = (const float*)d_in[0];
  const float* ts  = (const float*)d_in[1];
  const float* Wih = (const float*)d_in[2];
  const float* bih = (const float*)d_in[3];
  const float* Whh = (const float*)d_in[4];
  const float* bhh = (const float*)d_in[5];
  const float* Wou = (const float*)d_in[6];
  const float* bou = (const float*)d_in[7];
  float* out = (float*)d_out;

  char* ws = (char*)d_ws;
  size_t off = 0;
  auto alloc = [&](size_t bytes) -> void* {
    void* p = ws + off;
    off += (bytes + 255) & ~(size_t)255;
    return p;
  };
  unsigned short* Wa    = (unsigned short*)alloc((size_t)G3 * Dd * 2);        // 3.1MB
  unsigned short* WcT   = (unsigned short*)alloc((size_t)Cc * G3 * 2);        // 0.8MB
  unsigned short* Whb   = (unsigned short*)alloc((size_t)G3 * Hh * 2);        // 6.3MB
  unsigned short* Wob   = (unsigned short*)alloc((size_t)Cc * Hh * 2);        // 0.26MB
  int*            pid   = (int*)alloc((size_t)Bb * Tt * 4);                   // 0.26MB
  unsigned short* hring = (unsigned short*)alloc((size_t)SLOTS * Bb * Hh * 2);// 17.3MB
  unsigned short* Xb    = (unsigned short*)alloc((size_t)Bb * Tt * Dd * 2);   // 67.1MB
  unsigned short* gx    = (unsigned short*)alloc((size_t)Bb * TC * G3 * 2);   // 50.3MB
  if (ws_size < off) return;  // ~138MiB; round-9 proved >=163MiB exists

  int nX = Bb * Tt * Dd;
  k_cvt<<<nX / 2048, 256, 0, stream>>>(gru, Xb, nX);
  k_cvt<<<(G3 * Hh) / 2048, 256, 0, stream>>>(Whh, Whb, G3 * Hh);
  k_cvt<<<(Cc * Hh) / 2048, 256, 0, stream>>>(Wou, Wob, Cc * Hh);
  k_cvt_wa<<<(G3 * 64) / 256, 256, 0, stream>>>(Wih, Wa);
  k_cvt_wct<<<dim3(G3 / 256, Cc), 256, 0, stream>>>(Wih, WcT);
  k_pid<<<(Bb * Tt) / 256, 256, 0, stream>>>(ts, pid);
  size_t slotB = (size_t)Bb * Hh * 2;
  hipMemsetAsync(hring, 0, slotB, stream);                       // slot 0: h(0)=0
  hipMemsetAsync((char*)hring + slotB, 0xFF, 32 * slotB, stream);// slots 1..32 poison

  // prologue: gates for chunk 0
  k_gates<<<dim3(64, 24), 256, 0, stream>>>(Xb, Wa, WcT, bih, pid, gx, 0);

  for (int c = 0; c < NC; ++c) {
    int t0 = c * TC;
    if (c > 0)  // poison the slots scan(c) will write (after combo(c-1) read them)
      k_poison<<<dim3(2048), dim3(256), 0, stream>>>((u64*)hring, t0);
    k_scan<<<dim3(256), dim3(256), 0, stream>>>(Whb, bhh, gx, hring, t0);
    k_combo<<<dim3(1664), dim3(256), 0, stream>>>(
        Xb, Wa, WcT, bih, pid, gx, (c + 1 < NC) ? 1 : 0,
        hring, Wob, bou, out, t0);
  }
}

// Round 17
// 2332.332 us; speedup vs baseline: 1.1729x; 1.1729x over previous
//
#include <hip/hip_runtime.h>

// TerminalGRU: B=256 T=256 D=512 H=1024 C=128
// Round-17: REVERT to R14 verbatim (best proven: 2.319ms). R15 (XCD-local
// handshake) failed correctness; R16 (data-as-flag) regressed scan 174->219us
// (heavy re-poll traffic). The scan's ~5.4us/step is the serial MALL RTT
// chain (store-ack -> notify -> poll -> load, ~4 RTTs at agent scope) --
// latency-bound floor for this decomposition (MfmaUtil 11.5%, HBM 5%,
// VALU 12%: all idle; occupancy deliberately 1 block/CU for co-residency).
// Pipeline: prep+cvtX -> gates(0) -> loop{ scan(c); combo: gates(c+1)+logits(c) }

#define DEVI __device__ __forceinline__

typedef __bf16 bf16x8 __attribute__((ext_vector_type(8)));
typedef float f32x4 __attribute__((ext_vector_type(4)));
typedef unsigned long long u64;

static constexpr int Bb = 256, Tt = 256, Dd = 512, Hh = 1024, Cc = 128;
static constexpr int G3 = 3072, DC = 640, TC = 32, NC = Tt / TC;
static constexpr int SLOTS = TC + 1;  // 33-slot h ring
static constexpr int LDP = 72;        // LDS row stride (64 + 8 pad)

DEVI unsigned short f2b(float f) {
  union { float f; unsigned u; } v; v.f = f;
  unsigned r = v.u + 0x7FFFu + ((v.u >> 16) & 1u);
  return (unsigned short)(r >> 16);
}
DEVI float b2f(unsigned short h) {
  union { unsigned u; float f; } v; v.u = ((unsigned)h) << 16; return v.f;
}

// ---------------- prep kernels ----------------

__global__ __launch_bounds__(256) void k_cvt(const float* __restrict__ x,
                                             unsigned short* __restrict__ o, int n) {
  int i = (blockIdx.x * 256 + threadIdx.x) * 8;
  if (i >= n) return;
  float4 a = *(const float4*)(x + i), b = *(const float4*)(x + i + 4);
  uint4 u;
  u.x = (unsigned)f2b(a.x) | ((unsigned)f2b(a.y) << 16);
  u.y = (unsigned)f2b(a.z) | ((unsigned)f2b(a.w) << 16);
  u.z = (unsigned)f2b(b.x) | ((unsigned)f2b(b.y) << 16);
  u.w = (unsigned)f2b(b.z) | ((unsigned)f2b(b.w) << 16);
  *(uint4*)(o + i) = u;
}

__global__ __launch_bounds__(256) void k_cvt_wa(const float* __restrict__ Wih,
                                                unsigned short* __restrict__ Wa) {
  int u = blockIdx.x * 256 + threadIdx.x;
  int g = u >> 6, d = (u & 63) * 8;
  const float* p = Wih + (size_t)g * DC + d;
  float4 a = *(const float4*)p, b = *(const float4*)(p + 4);
  uint4 o;
  o.x = (unsigned)f2b(a.x) | ((unsigned)f2b(a.y) << 16);
  o.y = (unsigned)f2b(a.z) | ((unsigned)f2b(a.w) << 16);
  o.z = (unsigned)f2b(b.x) | ((unsigned)f2b(b.y) << 16);
  o.w = (unsigned)f2b(b.z) | ((unsigned)f2b(b.w) << 16);
  *(uint4*)(Wa + (size_t)g * Dd + d) = o;
}

__global__ __launch_bounds__(256) void k_cvt_wct(const float* __restrict__ Wih,
                                                 unsigned short* __restrict__ WcT) {
  int g = blockIdx.x * 256 + threadIdx.x;
  int c = blockIdx.y;
  WcT[(size_t)c * G3 + g] = f2b(Wih[(size_t)g * DC + Dd + c]);
}

__global__ __launch_bounds__(256) void k_pid(const float* __restrict__ ts,
                                             int* __restrict__ pid) {
  int bt = blockIdx.x * 256 + threadIdx.x;
  int t = bt & (Tt - 1);
  if (t == 0) { pid[bt] = -1; return; }
  const float* p = ts + (size_t)(bt - 1) * Cc;
  int id = 0;
  for (int c = 0; c < Cc; c += 4) {
    float4 v = *(const float4*)(p + c);
    if (v.x > 0.5f) id = c;
    if (v.y > 0.5f) id = c + 1;
    if (v.z > 0.5f) id = c + 2;
    if (v.w > 0.5f) id = c + 3;
  }
  pid[bt] = id;
}

// ---------------- gates tile: reg-staged LDS, BK=64 (R13 proven) ----------------
DEVI void gates_tile(int mi, int ni, const unsigned short* __restrict__ Xb,
                     const unsigned short* __restrict__ Wa,
                     const unsigned short* __restrict__ WcT,
                     const float* __restrict__ bih,
                     const int* __restrict__ pid,
                     unsigned short* __restrict__ gx, int t0c,
                     unsigned short* sA, unsigned short* sB) {
  const int m0 = mi * 128, n0 = ni * 128;
  const int tid = threadIdx.x;
  const int l = tid & 63, w = tid >> 6;
  const int wm = w >> 1, wn = w & 1;
  const int r0l = 64 * wm, c0l = 64 * wn;
  const int lr = l & 15, lk = (l >> 4) * 8;

  int srow[4], sq[4];
  size_t gA[4], gB[4];
#pragma unroll
  for (int c = 0; c < 4; ++c) {
    int ch = tid + c * 256;
    srow[c] = ch >> 3; sq[c] = ch & 7;
    int mrow = m0 + srow[c];
    gA[c] = ((size_t)((mrow >> 5) * Tt + t0c + (mrow & 31))) * Dd + sq[c] * 8;
    gB[c] = (size_t)(n0 + srow[c]) * Dd + sq[c] * 8;
  }

  f32x4 acc[4][4] = {};
  for (int ks = 0; ks < 8; ++ks) {
    int k0 = ks * 64;
    __syncthreads();
#pragma unroll
    for (int c = 0; c < 4; ++c) {
      bf16x8 av = *(const bf16x8*)(Xb + gA[c] + k0);
      bf16x8 bv = *(const bf16x8*)(Wa + gB[c] + k0);
      *(bf16x8*)(sA + srow[c] * LDP + sq[c] * 8) = av;
      *(bf16x8*)(sB + srow[c] * LDP + sq[c] * 8) = bv;
    }
    __syncthreads();
#pragma unroll
    for (int kk = 0; kk < 2; ++kk) {
      int kc = kk * 32 + lk;
      bf16x8 a[4], b[4];
#pragma unroll
      for (int mf = 0; mf < 4; ++mf)
        a[mf] = *(const bf16x8*)(sA + (r0l + 16 * mf + lr) * LDP + kc);
#pragma unroll
      for (int nf = 0; nf < 4; ++nf)
        b[nf] = *(const bf16x8*)(sB + (c0l + 16 * nf + lr) * LDP + kc);
#pragma unroll
      for (int mf = 0; mf < 4; ++mf)
#pragma unroll
        for (int nf = 0; nf < 4; ++nf)
          acc[mf][nf] = __builtin_amdgcn_mfma_f32_16x16x32_bf16(a[mf], b[nf], acc[mf][nf], 0, 0, 0);
    }
  }

  const int ri = (l >> 4) * 4;
  const int r0 = m0 + 64 * wm, c0 = n0 + 64 * wn;
  for (int mf = 0; mf < 4; ++mf) {
    int rowb = r0 + 16 * mf + ri;
    int pd[4];
#pragma unroll
    for (int i = 0; i < 4; ++i) {
      int rr = rowb + i;
      pd[i] = pid[(size_t)(rr >> 5) * Tt + t0c + (rr & 31)];
    }
    for (int nf = 0; nf < 4; ++nf) {
      int g = c0 + 16 * nf + lr;
      float bi = bih[g];
#pragma unroll
      for (int i = 0; i < 4; ++i) {
        float v = acc[mf][nf][i] + bi;
        if (pd[i] >= 0) v += b2f(WcT[(size_t)pd[i] * G3 + g]);
        gx[(size_t)(rowb + i) * G3 + g] = f2b(v);
      }
    }
  }
}

__global__ __launch_bounds__(256) void k_gates(const unsigned short* __restrict__ Xb,
                                               const unsigned short* __restrict__ Wa,
                                               const unsigned short* __restrict__ WcT,
                                               const float* __restrict__ bih,
                                               const int* __restrict__ pid,
                                               unsigned short* __restrict__ gx, int t0c) {
  __shared__ unsigned short sA[128 * LDP], sB[128 * LDP];
  gates_tile(blockIdx.x, blockIdx.y, Xb, Wa, WcT, bih, pid, gx, t0c, sA, sB);
}

// ---------------- logits tile (reads h straight from the ring) ----------------
DEVI void logits_tile(int blk, const unsigned short* __restrict__ hring,
                      const unsigned short* __restrict__ Wo,
                      const float* __restrict__ bout,
                      float* __restrict__ out, int t0) {
  int l = threadIdx.x & 63, w = threadIdx.x >> 6;
  int lr = l & 15, lk = (l >> 4) * 8;
  int r0 = blk * 64 + 16 * w;
  // this lane's A row: chunk-local m = r0+lr -> (b, tl) -> ring slot t0+tl+1
  int am = r0 + lr;
  int ab = am >> 5, atl = am & 31;
  const unsigned short* arow =
      hring + (size_t)((t0 + atl + 1) % SLOTS) * (Bb * Hh) + (size_t)ab * Hh;
  f32x4 acc[8] = {};
  for (int kk = 0; kk < 32; ++kk) {
    int k = kk * 32 + lk;
    bf16x8 a = *(const bf16x8*)(arow + k);
#pragma unroll
    for (int nf = 0; nf < 8; ++nf) {
      bf16x8 b = *(const bf16x8*)(Wo + (size_t)(16 * nf + lr) * Hh + k);
      acc[nf] = __builtin_amdgcn_mfma_f32_16x16x32_bf16(a, b, acc[nf], 0, 0, 0);
    }
  }
  int ri = (l >> 4) * 4;
  for (int nf = 0; nf < 8; ++nf) {
    int c = 16 * nf + lr;
    float bo = bout[c];
#pragma unroll
    for (int i = 0; i < 4; ++i) {
      int m = r0 + ri + i;
      int grow = (m >> 5) * Tt + t0 + (m & 31);
      out[(size_t)grow * Cc + c] = acc[nf][i] + bo;
    }
  }
}

// ---------------- combo: gates(c+1) + logits(c) ----------------
__global__ __launch_bounds__(256) void k_combo(
    const unsigned short* __restrict__ Xb, const unsigned short* __restrict__ Wa,
    const unsigned short* __restrict__ WcT, const float* __restrict__ bih,
    const int* __restrict__ pid, unsigned short* __restrict__ gxNext, int doGates,
    const unsigned short* __restrict__ hring, const unsigned short* __restrict__ Wob,
    const float* __restrict__ bou, float* __restrict__ outp, int t0) {
  __shared__ unsigned short sA[128 * LDP], sB[128 * LDP];
  int bid = blockIdx.x;
  if (bid < 1536) {
    if (doGates)
      gates_tile(bid & 63, bid >> 6, Xb, Wa, WcT, bih, pid, gxNext, t0 + TC, sA, sB);
  } else {
    logits_tile(bid - 1536, hring, Wob, bou, outp, t0);
  }
}

// ---------------- recurrent scan chunk (R14 proven) ----------------
// 256 blocks x 256 threads. mg = bid&7 (group, rows [32mg,+32)), cb = bid>>3
// (hcols [32cb,+32)). Wave w K-slice [256w,+256) -> producers 8w..8w+7 ONLY:
// per-wave poll of its own 8 notify words, MFMA starts as soon as they land.
__global__ __launch_bounds__(256, 1) void k_scan(const unsigned short* __restrict__ Whh,
                                                 const float* __restrict__ bhh,
                                                 const unsigned short* __restrict__ gx,
                                                 unsigned short* __restrict__ hring,
                                                 unsigned int* __restrict__ notify,
                                                 int t0) {
  __shared__ float red[4 * 32 * 100];  // [wave][row32][3*32 pad100] = 51.2KB
  const int tid = threadIdx.x;
  const int l = tid & 63, w = tid >> 6;
  const int bid = blockIdx.x;
  const int mg = bid & 7, cb = bid >> 3;
  const int lr = l & 15, lk = (l >> 4) * 8;
  const int hcolBase = 32 * cb;
  const int ri = (l >> 4) * 4;

  bf16x8 Breg[6][8];
#pragma unroll
  for (int nf = 0; nf < 6; ++nf) {
    int wrow = (nf >> 1) * Hh + hcolBase + (nf & 1) * 16 + lr;
#pragma unroll
    for (int kk = 0; kk < 8; ++kk) {
      int k = 256 * w + 32 * kk + lk;
      Breg[nf][kk] = *(const bf16x8*)(Whh + (size_t)wrow * Hh + k);
    }
  }

  const int erow = tid >> 3, ej0 = (tid & 7) * 4;
  const int eb = 32 * mg + erow;
  const int ecol = hcolBase + ej0;
  const float4 bhr4 = *(const float4*)(bhh + ecol);
  const float4 bhz4 = *(const float4*)(bhh + Hh + ecol);
  const float4 bhn4 = *(const float4*)(bhh + 2 * Hh + ecol);

  u64 hsave = 0;

  for (int tl = 0; tl < TC; ++tl) {
    const int t = t0 + tl;
    const unsigned short* hcur = hring + (size_t)(t % SLOTS) * (Bb * Hh);
    u64* hnq = (u64*)hring + (size_t)((t + 1) % SLOTS) * (Bb * Hh / 4);

    const size_t gxo = (size_t)(eb * TC + tl) * G3;
    uint2 gr = *(const uint2*)(gx + gxo + ecol);
    uint2 gz = *(const uint2*)(gx + gxo + Hh + ecol);
    uint2 gn = *(const uint2*)(gx + gxo + 2 * Hh + ecol);

    // per-wave wait: only this wave's 8 K-slice producers
    if (t > 0) {
      const unsigned int* np = notify + (mg << 6) + 8 * w + (l & 7);
      for (;;) {
        unsigned int v = __hip_atomic_load(np, __ATOMIC_RELAXED,
                                           __HIP_MEMORY_SCOPE_AGENT);
        if (__all((int)(v >= (unsigned)t))) break;
      }
    }
    asm volatile("" ::: "memory");

    u64 hprev = (tl == 0) ? *(const u64*)(hcur + (size_t)eb * Hh + ecol) : hsave;

    f32x4 acc[2][6] = {};
#pragma unroll
    for (int kk = 0; kk < 8; ++kk) {
      int k = 256 * w + 32 * kk + lk;
      bf16x8 a[2];
#pragma unroll
      for (int mf = 0; mf < 2; ++mf)
        a[mf] = *(const bf16x8*)(hcur + (size_t)(32 * mg + 16 * mf + lr) * Hh + k);
#pragma unroll
      for (int mf = 0; mf < 2; ++mf)
#pragma unroll
        for (int nf = 0; nf < 6; ++nf)
          acc[mf][nf] = __builtin_amdgcn_mfma_f32_16x16x32_bf16(a[mf], Breg[nf][kk], acc[mf][nf], 0, 0, 0);
    }

#pragma unroll
    for (int mf = 0; mf < 2; ++mf)
#pragma unroll
      for (int nf = 0; nf < 6; ++nf)
#pragma unroll
        for (int i = 0; i < 4; ++i)
          red[(w * 32 + 16 * mf + ri + i) * 100 + (nf >> 1) * 32 + (nf & 1) * 16 + lr] = acc[mf][nf][i];
    __syncthreads();

    f32x4 vr = {}, vz = {}, vn = {};
#pragma unroll
    for (int w2 = 0; w2 < 4; ++w2) {
      const float* rp = &red[(w2 * 32 + erow) * 100];
      vr += *(const f32x4*)(rp + ej0);
      vz += *(const f32x4*)(rp + 32 + ej0);
      vn += *(const f32x4*)(rp + 64 + ej0);
    }
    unsigned short grs[4] = {(unsigned short)gr.x, (unsigned short)(gr.x >> 16),
                             (unsigned short)gr.y, (unsigned short)(gr.y >> 16)};
    unsigned short gzs[4] = {(unsigned short)gz.x, (unsigned short)(gz.x >> 16),
                             (unsigned short)gz.y, (unsigned short)(gz.y >> 16)};
    unsigned short gns[4] = {(unsigned short)gn.x, (unsigned short)(gn.x >> 16),
                             (unsigned short)gn.y, (unsigned short)(gn.y >> 16)};
    u64 ho = 0;
#pragma unroll
    for (int i = 0; i < 4; ++i) {
      float hr = vr[i] + (&bhr4.x)[i];
      float hz = vz[i] + (&bhz4.x)[i];
      float hn = vn[i] + (&bhn4.x)[i];
      float xr = b2f(grs[i]), xz = b2f(gzs[i]), xn = b2f(gns[i]);
      float rg = 1.f / (1.f + __expf(-(xr + hr)));
      float zg = 1.f / (1.f + __expf(-(xz + hz)));
      float pre = xn + rg * hn;
      pre = fminf(fmaxf(pre, -15.f), 15.f);
      float e = __expf(-2.f * pre);
      float ng = (1.f - e) / (1.f + e);
      float hp = b2f((unsigned short)(hprev >> (16 * i)));
      float hv = (1.f - zg) * ng + zg * hp;
      ho |= (u64)f2b(hv) << (16 * i);
    }
    __hip_atomic_store(hnq + ((size_t)eb * Hh + ecol) / 4, ho,
                       __ATOMIC_RELAXED, __HIP_MEMORY_SCOPE_AGENT);
    hsave = ho;

    asm volatile("s_waitcnt vmcnt(0)" ::: "memory");  // h stores acked at MALL
    __syncthreads();  // all waves drained; also protects red[] reuse
    if (tid == 0)
      __hip_atomic_store(notify + (mg << 6) + cb, (unsigned)(t + 1),
                         __ATOMIC_RELAXED, __HIP_MEMORY_SCOPE_AGENT);
  }
}

// ---------------- launch ----------------
extern "C" void kernel_launch(void* const* d_in, const int* in_sizes, int n_in,
                              void* d_out, int out_size, void* d_ws, size_t ws_size,
                              hipStream_t stream) {
  const float* gru = (const float*)d_in[0];
  const float* ts  = (const float*)d_in[1];
  const float* Wih = (const float*)d_in[2];
  const float* bih = (const float*)d_in[3];
  const float* Whh = (const float*)d_in[4];
  const float* bhh = (const float*)d_in[5];
  const float* Wou = (const float*)d_in[6];
  const float* bou = (const float*)d_in[7];
  float* out = (float*)d_out;

  char* ws = (char*)d_ws;
  size_t off = 0;
  auto alloc = [&](size_t bytes) -> void* {
    void* p = ws + off;
    off += (bytes + 255) & ~(size_t)255;
    return p;
  };
  unsigned short* Wa    = (unsigned short*)alloc((size_t)G3 * Dd * 2);        // 3.1MB
  unsigned short* WcT   = (unsigned short*)alloc((size_t)Cc * G3 * 2);        // 0.8MB
  unsigned short* Whb   = (unsigned short*)alloc((size_t)G3 * Hh * 2);        // 6.3MB
  unsigned short* Wob   = (unsigned short*)alloc((size_t)Cc * Hh * 2);        // 0.26MB
  int*            pid   = (int*)alloc((size_t)Bb * Tt * 4);                   // 0.26MB
  unsigned short* hring = (unsigned short*)alloc((size_t)SLOTS * Bb * Hh * 2);// 17.3MB
  unsigned int*   nfy   = (unsigned int*)alloc((size_t)8 * 64 * 4);
  unsigned short* Xb    = (unsigned short*)alloc((size_t)Bb * Tt * Dd * 2);   // 67.1MB
  unsigned short* gx    = (unsigned short*)alloc((size_t)Bb * TC * G3 * 2);   // 50.3MB
  if (ws_size < off) return;  // ~138MiB; round-9 proved >=163MiB exists

  int nX = Bb * Tt * Dd;
  k_cvt<<<nX / 2048, 256, 0, stream>>>(gru, Xb, nX);
  k_cvt<<<(G3 * Hh) / 2048, 256, 0, stream>>>(Whh, Whb, G3 * Hh);
  k_cvt<<<(Cc * Hh) / 2048, 256, 0, stream>>>(Wou, Wob, Cc * Hh);
  k_cvt_wa<<<(G3 * 64) / 256, 256, 0, stream>>>(Wih, Wa);
  k_cvt_wct<<<dim3(G3 / 256, Cc), 256, 0, stream>>>(Wih, WcT);
  k_pid<<<(Bb * Tt) / 256, 256, 0, stream>>>(ts, pid);
  hipMemsetAsync(hring, 0, (size_t)Bb * Hh * 2, stream);  // slot 0 = h(0) = 0
  hipMemsetAsync(nfy, 0, (size_t)8 * 64 * 4, stream);

  // prologue: gates for chunk 0
  k_gates<<<dim3(64, 24), 256, 0, stream>>>(Xb, Wa, WcT, bih, pid, gx, 0);

  for (int c = 0; c < NC; ++c) {
    int t0 = c * TC;
    k_scan<<<dim3(256), dim3(256), 0, stream>>>(Whb, bhh, gx, hring, nfy, t0);
    k_combo<<<dim3(1664), dim3(256), 0, stream>>>(
        Xb, Wa, WcT, bih, pid, gx, (c + 1 < NC) ? 1 : 0,
        hring, Wob, bou, out, t0);
  }
}

// Round 18
// 2273.477 us; speedup vs baseline: 1.2033x; 1.0259x over previous
//
#include <hip/hip_runtime.h>

// TerminalGRU: B=256 T=256 D=512 H=1024 C=128
// Round-18: scan untouched (R14/R17 proven; latency floor 256 x ~5.4us MALL
// chain, 3 falsified attacks). Lever: gates GEMM staging -> m97 structure
// (ladder step 2->3: reg-staged 517 TF -> global_load_lds 874 TF). BK=32,
// linear LDS [128][32] per operand, 4x global_load_lds(16B)/thread/K-step
// (per-lane global addr handles scattered A rows; LDS dest wave-uniform
// base + lane*16), ds_read_b128 fragments, 16 MFMA/step. Same K order ->
// bit-identical. Applied to prologue k_gates + combo gates path.
// Pipeline: prep+cvtX -> gates(0) -> loop{ scan(c); combo: gates(c+1)+logits(c) }

#define DEVI __device__ __forceinline__

typedef __bf16 bf16x8 __attribute__((ext_vector_type(8)));
typedef float f32x4 __attribute__((ext_vector_type(4)));
typedef unsigned long long u64;

static constexpr int Bb = 256, Tt = 256, Dd = 512, Hh = 1024, Cc = 128;
static constexpr int G3 = 3072, DC = 640, TC = 32, NC = Tt / TC;
static constexpr int SLOTS = TC + 1;  // 33-slot h ring

DEVI unsigned short f2b(float f) {
  union { float f; unsigned u; } v; v.f = f;
  unsigned r = v.u + 0x7FFFu + ((v.u >> 16) & 1u);
  return (unsigned short)(r >> 16);
}
DEVI float b2f(unsigned short h) {
  union { unsigned u; float f; } v; v.u = ((unsigned)h) << 16; return v.f;
}

DEVI void gload16(const unsigned short* g, unsigned short* l) {
  __builtin_amdgcn_global_load_lds(
      (const __attribute__((address_space(1))) unsigned int*)g,
      (__attribute__((address_space(3))) unsigned int*)l, 16, 0, 0);
}

// ---------------- prep kernels ----------------

__global__ __launch_bounds__(256) void k_cvt(const float* __restrict__ x,
                                             unsigned short* __restrict__ o, int n) {
  int i = (blockIdx.x * 256 + threadIdx.x) * 8;
  if (i >= n) return;
  float4 a = *(const float4*)(x + i), b = *(const float4*)(x + i + 4);
  uint4 u;
  u.x = (unsigned)f2b(a.x) | ((unsigned)f2b(a.y) << 16);
  u.y = (unsigned)f2b(a.z) | ((unsigned)f2b(a.w) << 16);
  u.z = (unsigned)f2b(b.x) | ((unsigned)f2b(b.y) << 16);
  u.w = (unsigned)f2b(b.z) | ((unsigned)f2b(b.w) << 16);
  *(uint4*)(o + i) = u;
}

__global__ __launch_bounds__(256) void k_cvt_wa(const float* __restrict__ Wih,
                                                unsigned short* __restrict__ Wa) {
  int u = blockIdx.x * 256 + threadIdx.x;
  int g = u >> 6, d = (u & 63) * 8;
  const float* p = Wih + (size_t)g * DC + d;
  float4 a = *(const float4*)p, b = *(const float4*)(p + 4);
  uint4 o;
  o.x = (unsigned)f2b(a.x) | ((unsigned)f2b(a.y) << 16);
  o.y = (unsigned)f2b(a.z) | ((unsigned)f2b(a.w) << 16);
  o.z = (unsigned)f2b(b.x) | ((unsigned)f2b(b.y) << 16);
  o.w = (unsigned)f2b(b.z) | ((unsigned)f2b(b.w) << 16);
  *(uint4*)(Wa + (size_t)g * Dd + d) = o;
}

__global__ __launch_bounds__(256) void k_cvt_wct(const float* __restrict__ Wih,
                                                 unsigned short* __restrict__ WcT) {
  int g = blockIdx.x * 256 + threadIdx.x;
  int c = blockIdx.y;
  WcT[(size_t)c * G3 + g] = f2b(Wih[(size_t)g * DC + Dd + c]);
}

__global__ __launch_bounds__(256) void k_pid(const float* __restrict__ ts,
                                             int* __restrict__ pid) {
  int bt = blockIdx.x * 256 + threadIdx.x;
  int t = bt & (Tt - 1);
  if (t == 0) { pid[bt] = -1; return; }
  const float* p = ts + (size_t)(bt - 1) * Cc;
  int id = 0;
  for (int c = 0; c < Cc; c += 4) {
    float4 v = *(const float4*)(p + c);
    if (v.x > 0.5f) id = c;
    if (v.y > 0.5f) id = c + 1;
    if (v.z > 0.5f) id = c + 2;
    if (v.w > 0.5f) id = c + 3;
  }
  pid[bt] = id;
}

// ---------------- gates tile: m97 structure (global_load_lds, BK=32) ----------------
// sA/sB: linear [128][32] bf16 (8KB each). Per K-step: 4 passes x 256 threads
// stage 1024 x 16B slots (512 A + 512 B); slot = p*256+tid -> row slot>>2,
// quarter slot&3. LDS dest per pass/wave is uniform base + lane*16.
DEVI void gates_tile(int mi, int ni, const unsigned short* __restrict__ Xb,
                     const unsigned short* __restrict__ Wa,
                     const unsigned short* __restrict__ WcT,
                     const float* __restrict__ bih,
                     const int* __restrict__ pid,
                     unsigned short* __restrict__ gx, int t0c,
                     unsigned short* sA, unsigned short* sB) {
  const int m0 = mi * 128, n0 = ni * 128;
  const int tid = threadIdx.x;
  const int l = tid & 63, w = tid >> 6;
  const int wm = w >> 1, wn = w & 1;
  const int r0l = 64 * wm, c0l = 64 * wn;
  const int lr = l & 15, lk = (l >> 4) * 8;

  const unsigned short* gsrc[4];
  unsigned short* ldst[4];
#pragma unroll
  for (int p = 0; p < 4; ++p) {
    int slot = p * 256 + tid;
    if (slot < 512) {
      int row = slot >> 2, q = slot & 3;
      int mrow = m0 + row;
      gsrc[p] = Xb + ((size_t)((mrow >> 5) * Tt + t0c + (mrow & 31))) * Dd + q * 8;
      ldst[p] = sA + (size_t)(p * 256 + 64 * w) * 8;      // wave-uniform base
    } else {
      int s2 = slot - 512;
      int row = s2 >> 2, q = s2 & 3;
      gsrc[p] = Wa + (size_t)(n0 + row) * Dd + q * 8;
      ldst[p] = sB + (size_t)((p - 2) * 256 + 64 * w) * 8;  // wave-uniform base
    }
  }

  f32x4 acc[4][4] = {};
  for (int ks = 0; ks < 16; ++ks) {
    int k0 = ks * 32;
    __syncthreads();  // previous step's LDS readers done
#pragma unroll
    for (int p = 0; p < 4; ++p)
      gload16(gsrc[p] + k0, ldst[p]);
    __syncthreads();  // staging (vmcnt) drained
    bf16x8 a[4], b[4];
#pragma unroll
    for (int mf = 0; mf < 4; ++mf)
      a[mf] = *(const bf16x8*)(sA + (r0l + 16 * mf + lr) * 32 + lk);
#pragma unroll
    for (int nf = 0; nf < 4; ++nf)
      b[nf] = *(const bf16x8*)(sB + (c0l + 16 * nf + lr) * 32 + lk);
#pragma unroll
    for (int mf = 0; mf < 4; ++mf)
#pragma unroll
      for (int nf = 0; nf < 4; ++nf)
        acc[mf][nf] = __builtin_amdgcn_mfma_f32_16x16x32_bf16(a[mf], b[nf], acc[mf][nf], 0, 0, 0);
  }

  const int ri = (l >> 4) * 4;
  const int r0 = m0 + 64 * wm, c0 = n0 + 64 * wn;
  for (int mf = 0; mf < 4; ++mf) {
    int rowb = r0 + 16 * mf + ri;
    int pd[4];
#pragma unroll
    for (int i = 0; i < 4; ++i) {
      int rr = rowb + i;
      pd[i] = pid[(size_t)(rr >> 5) * Tt + t0c + (rr & 31)];
    }
    for (int nf = 0; nf < 4; ++nf) {
      int g = c0 + 16 * nf + lr;
      float bi = bih[g];
#pragma unroll
      for (int i = 0; i < 4; ++i) {
        float v = acc[mf][nf][i] + bi;
        if (pd[i] >= 0) v += b2f(WcT[(size_t)pd[i] * G3 + g]);
        gx[(size_t)(rowb + i) * G3 + g] = f2b(v);
      }
    }
  }
}

__global__ __launch_bounds__(256) void k_gates(const unsigned short* __restrict__ Xb,
                                               const unsigned short* __restrict__ Wa,
                                               const unsigned short* __restrict__ WcT,
                                               const float* __restrict__ bih,
                                               const int* __restrict__ pid,
                                               unsigned short* __restrict__ gx, int t0c) {
  __shared__ unsigned short sA[128 * 32], sB[128 * 32];
  gates_tile(blockIdx.x, blockIdx.y, Xb, Wa, WcT, bih, pid, gx, t0c, sA, sB);
}

// ---------------- logits tile (reads h straight from the ring) ----------------
DEVI void logits_tile(int blk, const unsigned short* __restrict__ hring,
                      const unsigned short* __restrict__ Wo,
                      const float* __restrict__ bout,
                      float* __restrict__ out, int t0) {
  int l = threadIdx.x & 63, w = threadIdx.x >> 6;
  int lr = l & 15, lk = (l >> 4) * 8;
  int r0 = blk * 64 + 16 * w;
  int am = r0 + lr;
  int ab = am >> 5, atl = am & 31;
  const unsigned short* arow =
      hring + (size_t)((t0 + atl + 1) % SLOTS) * (Bb * Hh) + (size_t)ab * Hh;
  f32x4 acc[8] = {};
  for (int kk = 0; kk < 32; ++kk) {
    int k = kk * 32 + lk;
    bf16x8 a = *(const bf16x8*)(arow + k);
#pragma unroll
    for (int nf = 0; nf < 8; ++nf) {
      bf16x8 b = *(const bf16x8*)(Wo + (size_t)(16 * nf + lr) * Hh + k);
      acc[nf] = __builtin_amdgcn_mfma_f32_16x16x32_bf16(a, b, acc[nf], 0, 0, 0);
    }
  }
  int ri = (l >> 4) * 4;
  for (int nf = 0; nf < 8; ++nf) {
    int c = 16 * nf + lr;
    float bo = bout[c];
#pragma unroll
    for (int i = 0; i < 4; ++i) {
      int m = r0 + ri + i;
      int grow = (m >> 5) * Tt + t0 + (m & 31);
      out[(size_t)grow * Cc + c] = acc[nf][i] + bo;
    }
  }
}

// ---------------- combo: gates(c+1) + logits(c) ----------------
__global__ __launch_bounds__(256) void k_combo(
    const unsigned short* __restrict__ Xb, const unsigned short* __restrict__ Wa,
    const unsigned short* __restrict__ WcT, const float* __restrict__ bih,
    const int* __restrict__ pid, unsigned short* __restrict__ gxNext, int doGates,
    const unsigned short* __restrict__ hring, const unsigned short* __restrict__ Wob,
    const float* __restrict__ bou, float* __restrict__ outp, int t0) {
  __shared__ unsigned short sA[128 * 32], sB[128 * 32];
  int bid = blockIdx.x;
  if (bid < 1536) {
    if (doGates)
      gates_tile(bid & 63, bid >> 6, Xb, Wa, WcT, bih, pid, gxNext, t0 + TC, sA, sB);
  } else {
    logits_tile(bid - 1536, hring, Wob, bou, outp, t0);
  }
}

// ---------------- recurrent scan chunk (R14/R17 proven, unchanged) ----------------
__global__ __launch_bounds__(256, 1) void k_scan(const unsigned short* __restrict__ Whh,
                                                 const float* __restrict__ bhh,
                                                 const unsigned short* __restrict__ gx,
                                                 unsigned short* __restrict__ hring,
                                                 unsigned int* __restrict__ notify,
                                                 int t0) {
  __shared__ float red[4 * 32 * 100];  // [wave][row32][3*32 pad100] = 51.2KB
  const int tid = threadIdx.x;
  const int l = tid & 63, w = tid >> 6;
  const int bid = blockIdx.x;
  const int mg = bid & 7, cb = bid >> 3;
  const int lr = l & 15, lk = (l >> 4) * 8;
  const int hcolBase = 32 * cb;
  const int ri = (l >> 4) * 4;

  bf16x8 Breg[6][8];
#pragma unroll
  for (int nf = 0; nf < 6; ++nf) {
    int wrow = (nf >> 1) * Hh + hcolBase + (nf & 1) * 16 + lr;
#pragma unroll
    for (int kk = 0; kk < 8; ++kk) {
      int k = 256 * w + 32 * kk + lk;
      Breg[nf][kk] = *(const bf16x8*)(Whh + (size_t)wrow * Hh + k);
    }
  }

  const int erow = tid >> 3, ej0 = (tid & 7) * 4;
  const int eb = 32 * mg + erow;
  const int ecol = hcolBase + ej0;
  const float4 bhr4 = *(const float4*)(bhh + ecol);
  const float4 bhz4 = *(const float4*)(bhh + Hh + ecol);
  const float4 bhn4 = *(const float4*)(bhh + 2 * Hh + ecol);

  u64 hsave = 0;

  for (int tl = 0; tl < TC; ++tl) {
    const int t = t0 + tl;
    const unsigned short* hcur = hring + (size_t)(t % SLOTS) * (Bb * Hh);
    u64* hnq = (u64*)hring + (size_t)((t + 1) % SLOTS) * (Bb * Hh / 4);

    const size_t gxo = (size_t)(eb * TC + tl) * G3;
    uint2 gr = *(const uint2*)(gx + gxo + ecol);
    uint2 gz = *(const uint2*)(gx + gxo + Hh + ecol);
    uint2 gn = *(const uint2*)(gx + gxo + 2 * Hh + ecol);

    // per-wave wait: only this wave's 8 K-slice producers
    if (t > 0) {
      const unsigned int* np = notify + (mg << 6) + 8 * w + (l & 7);
      for (;;) {
        unsigned int v = __hip_atomic_load(np, __ATOMIC_RELAXED,
                                           __HIP_MEMORY_SCOPE_AGENT);
        if (__all((int)(v >= (unsigned)t))) break;
      }
    }
    asm volatile("" ::: "memory");

    u64 hprev = (tl == 0) ? *(const u64*)(hcur + (size_t)eb * Hh + ecol) : hsave;

    f32x4 acc[2][6] = {};
#pragma unroll
    for (int kk = 0; kk < 8; ++kk) {
      int k = 256 * w + 32 * kk + lk;
      bf16x8 a[2];
#pragma unroll
      for (int mf = 0; mf < 2; ++mf)
        a[mf] = *(const bf16x8*)(hcur + (size_t)(32 * mg + 16 * mf + lr) * Hh + k);
#pragma unroll
      for (int mf = 0; mf < 2; ++mf)
#pragma unroll
        for (int nf = 0; nf < 6; ++nf)
          acc[mf][nf] = __builtin_amdgcn_mfma_f32_16x16x32_bf16(a[mf], Breg[nf][kk], acc[mf][nf], 0, 0, 0);
    }

#pragma unroll
    for (int mf = 0; mf < 2; ++mf)
#pragma unroll
      for (int nf = 0; nf < 6; ++nf)
#pragma unroll
        for (int i = 0; i < 4; ++i)
          red[(w * 32 + 16 * mf + ri + i) * 100 + (nf >> 1) * 32 + (nf & 1) * 16 + lr] = acc[mf][nf][i];
    __syncthreads();

    f32x4 vr = {}, vz = {}, vn = {};
#pragma unroll
    for (int w2 = 0; w2 < 4; ++w2) {
      const float* rp = &red[(w2 * 32 + erow) * 100];
      vr += *(const f32x4*)(rp + ej0);
      vz += *(const f32x4*)(rp + 32 + ej0);
      vn += *(const f32x4*)(rp + 64 + ej0);
    }
    unsigned short grs[4] = {(unsigned short)gr.x, (unsigned short)(gr.x >> 16),
                             (unsigned short)gr.y, (unsigned short)(gr.y >> 16)};
    unsigned short gzs[4] = {(unsigned short)gz.x, (unsigned short)(gz.x >> 16),
                             (unsigned short)gz.y, (unsigned short)(gz.y >> 16)};
    unsigned short gns[4] = {(unsigned short)gn.x, (unsigned short)(gn.x >> 16),
                             (unsigned short)gn.y, (unsigned short)(gn.y >> 16)};
    u64 ho = 0;
#pragma unroll
    for (int i = 0; i < 4; ++i) {
      float hr = vr[i] + (&bhr4.x)[i];
      float hz = vz[i] + (&bhz4.x)[i];
      float hn = vn[i] + (&bhn4.x)[i];
      float xr = b2f(grs[i]), xz = b2f(gzs[i]), xn = b2f(gns[i]);
      float rg = 1.f / (1.f + __expf(-(xr + hr)));
      float zg = 1.f / (1.f + __expf(-(xz + hz)));
      float pre = xn + rg * hn;
      pre = fminf(fmaxf(pre, -15.f), 15.f);
      float e = __expf(-2.f * pre);
      float ng = (1.f - e) / (1.f + e);
      float hp = b2f((unsigned short)(hprev >> (16 * i)));
      float hv = (1.f - zg) * ng + zg * hp;
      ho |= (u64)f2b(hv) << (16 * i);
    }
    __hip_atomic_store(hnq + ((size_t)eb * Hh + ecol) / 4, ho,
                       __ATOMIC_RELAXED, __HIP_MEMORY_SCOPE_AGENT);
    hsave = ho;

    asm volatile("s_waitcnt vmcnt(0)" ::: "memory");  // h stores acked at MALL
    __syncthreads();  // all waves drained; also protects red[] reuse
    if (tid == 0)
      __hip_atomic_store(notify + (mg << 6) + cb, (unsigned)(t + 1),
                         __ATOMIC_RELAXED, __HIP_MEMORY_SCOPE_AGENT);
  }
}

// ---------------- launch ----------------
extern "C" void kernel_launch(void* const* d_in, const int* in_sizes, int n_in,
                              void* d_out, int out_size, void* d_ws, size_t ws_size,
                              hipStream_t stream) {
  const float* gru = (const float*)d_in[0];
  const float* ts  = (const float*)d_in[1];
  const float* Wih = (const float*)d_in[2];
  const float* bih = (const float*)d_in[3];
  const float* Whh = (const float*)d_in[4];
  const float* bhh = (const float*)d_in[5];
  const float* Wou = (const float*)d_in[6];
  const float* bou = (const float*)d_in[7];
  float* out = (float*)d_out;

  char* ws = (char*)d_ws;
  size_t off = 0;
  auto alloc = [&](size_t bytes) -> void* {
    void* p = ws + off;
    off += (bytes + 255) & ~(size_t)255;
    return p;
  };
  unsigned short* Wa    = (unsigned short*)alloc((size_t)G3 * Dd * 2);        // 3.1MB
  unsigned short* WcT   = (unsigned short*)alloc((size_t)Cc * G3 * 2);        // 0.8MB
  unsigned short* Whb   = (unsigned short*)alloc((size_t)G3 * Hh * 2);        // 6.3MB
  unsigned short* Wob   = (unsigned short*)alloc((size_t)Cc * Hh * 2);        // 0.26MB
  int*            pid   = (int*)alloc((size_t)Bb * Tt * 4);                   // 0.26MB
  unsigned short* hring = (unsigned short*)alloc((size_t)SLOTS * Bb * Hh * 2);// 17.3MB
  unsigned int*   nfy   = (unsigned int*)alloc((size_t)8 * 64 * 4);
  unsigned short* Xb    = (unsigned short*)alloc((size_t)Bb * Tt * Dd * 2);   // 67.1MB
  unsigned short* gx    = (unsigned short*)alloc((size_t)Bb * TC * G3 * 2);   // 50.3MB
  if (ws_size < off) return;  // ~138MiB; round-9 proved >=163MiB exists

  int nX = Bb * Tt * Dd;
  k_cvt<<<nX / 2048, 256, 0, stream>>>(gru, Xb, nX);
  k_cvt<<<(G3 * Hh) / 2048, 256, 0, stream>>>(Whh, Whb, G3 * Hh);
  k_cvt<<<(Cc * Hh) / 2048, 256, 0, stream>>>(Wou, Wob, Cc * Hh);
  k_cvt_wa<<<(G3 * 64) / 256, 256, 0, stream>>>(Wih, Wa);
  k_cvt_wct<<<dim3(G3 / 256, Cc), 256, 0, stream>>>(Wih, WcT);
  k_pid<<<(Bb * Tt) / 256, 256, 0, stream>>>(ts, pid);
  hipMemsetAsync(hring, 0, (size_t)Bb * Hh * 2, stream);  // slot 0 = h(0) = 0
  hipMemsetAsync(nfy, 0, (size_t)8 * 64 * 4, stream);

  // prologue: gates for chunk 0
  k_gates<<<dim3(64, 24), 256, 0, stream>>>(Xb, Wa, WcT, bih, pid, gx, 0);

  for (int c = 0; c < NC; ++c) {
    int t0 = c * TC;
    k_scan<<<dim3(256), dim3(256), 0, stream>>>(Whb, bhh, gx, hring, nfy, t0);
    k_combo<<<dim3(1664), dim3(256), 0, stream>>>(
        Xb, Wa, WcT, bih, pid, gx, (c + 1 < NC) ? 1 : 0,
        hring, Wob, bou, out, t0);
  }
}